// Round 8
// baseline (392.545 us; speedup 1.0000x reference)
//
#include <hip/hip_runtime.h>
#include <hip/hip_fp16.h>
#include <math.h>

typedef float  f32x4 __attribute__((ext_vector_type(4)));
typedef double f64x4 __attribute__((ext_vector_type(4)));
typedef unsigned short u16x8 __attribute__((ext_vector_type(8)));

#define NPTS 4096
#define DIM  512
#define BK   32
#define LDP  68
#define NTB  64
#define NTILES (NTB*(NTB+1)/2)       // 2080 upper-tri tiles

// ws layout (doubles)
#define WS_U_A   0
#define WS_U_B   4096
#define WS_PAB   8192
#define WS_PAA   (8192 + NTILES)
#define WS_PBB   (8192 + 2*NTILES)
#define WS_SQA   (8192 + 3*NTILES)
#define WS_SQB   (WS_SQA + NPTS)
#define WS_ZERO_DOUBLES WS_SQA

__device__ __forceinline__ void tri_decode(int t, int& bi, int& bj) {
  int r = (int)((sqrt(8.0 * (double)t + 1.0) - 1.0) * 0.5);
  while ((r + 1) * (r + 2) / 2 <= t) ++r;
  while (r * (r + 1) / 2 > t) --r;
  bj = r; bi = t - r * (r + 1) / 2;   // bi <= bj
}

// ---------------- sq kernel: sq[i] = sum_k x[i][k]^2 (double) -------------
__global__ __launch_bounds__(256) void sq_kernel(const float* __restrict__ fa,
                                                 const float* __restrict__ fb,
                                                 double* __restrict__ ws) {
  int wave = threadIdx.x >> 6, lane = threadIdx.x & 63;
  int row = blockIdx.x * 4 + wave;
  const float* src = blockIdx.y ? fb : fa;
  double*      dst = blockIdx.y ? (ws + WS_SQB) : (ws + WS_SQA);
  const f32x4* p = (const f32x4*)(src + (size_t)row * DIM);
  double s = 0.0;
#pragma unroll
  for (int c = 0; c < DIM / 4 / 64; ++c) {
    f32x4 v = p[lane + c * 64];
    s += (double)v[0]*v[0] + (double)v[1]*v[1] + (double)v[2]*v[2] + (double)v[3]*v[3];
  }
  for (int off = 32; off; off >>= 1) s += __shfl_down(s, off);
  if (lane == 0) dst[row] = s;
}

// ---- named-register accumulator machinery (no arrays -> no scratch risk) ----
#define ROWS8(X) X(0) X(1) X(2) X(3) X(4) X(5) X(6) X(7)

#define DECL_ROW(m) \
  f32x4 a##m##_0 = {0.f,0.f,0.f,0.f}, a##m##_1 = {0.f,0.f,0.f,0.f}; \
  f64x4 d##m##_0 = {0.0,0.0,0.0,0.0}, d##m##_1 = {0.0,0.0,0.0,0.0};

#define FMA_ROW(m) { \
  const float s_ = (m) < 4 ? vI0[(m) & 3] : vI1[(m) & 3]; \
  const f32x4 sv_ = {s_, s_, s_, s_}; \
  a##m##_0 = __builtin_elementwise_fma(sv_, vJ0, a##m##_0); \
  a##m##_1 = __builtin_elementwise_fma(sv_, vJ1, a##m##_1); }

#define FLUSH_ROW(m) \
  d##m##_0 += __builtin_convertvector(a##m##_0, f64x4); \
  d##m##_1 += __builtin_convertvector(a##m##_1, f64x4); \
  a##m##_0 = (f32x4){0.f,0.f,0.f,0.f}; \
  a##m##_1 = (f32x4){0.f,0.f,0.f,0.f};

#define STORE_ROW(m) \
  accD[m][0] = d##m##_0[0]; accD[m][1] = d##m##_0[1]; \
  accD[m][2] = d##m##_0[2]; accD[m][3] = d##m##_0[3]; \
  accD[m][4] = d##m##_1[0]; accD[m][5] = d##m##_1[1]; \
  accD[m][6] = d##m##_1[2]; accD[m][7] = d##m##_1[3];

// ---------------- fused gram + fp16 distances + all statistics ----------------
// 128 threads = 2 waves: wave0 -> matrix A, wave1 -> matrix B. 8x8 tile/thread.
// NUMERICS FROZEN: per-(i,j) fp32 fma chain, kk ascending within each BK=32
// chunk, f64 flush per chunk, d2 = si+sj-2*accD, d = fp16_rne((float)sqrt(d2)),
// diagonal forced 0. (Thread remapping & vectorization are bit-invariant.)
__attribute__((amdgpu_waves_per_eu(2, 2)))
__global__ void __launch_bounds__(128, 2)
gram_kernel(const float* __restrict__ fa, const float* __restrict__ fb,
            double* __restrict__ ws)
{
  int bi, bj; tri_decode(blockIdx.x, bi, bj);
  const int i0 = bi * 64, j0 = bj * 64;
  const bool diag = (bi == bj);

  __shared__ alignas(16) float smem[4 * BK * LDP];   // 34816 B staging
  float* sAI_ = smem;
  float* sAJ_ = smem + BK * LDP;
  float* sBI_ = smem + 2 * BK * LDP;
  float* sBJ_ = smem + 3 * BK * LDP;
  __shared__ double wred[2][2];
  // after the k-loop the staging LDS is dead; wave1 publishes fp16 bits here
  unsigned short* dbufB = (unsigned short*)smem;     // 64 rows x 72 u16

  const int t    = threadIdx.x;
  const int wave = t >> 6, lane = t & 63;
  const int lx   = lane & 7, ly = lane >> 3;

  ROWS8(DECL_ROW)

  const int rr = lane;                         // staging row = lane (0..63)
  const float* pI = (wave ? sBI_ : sAI_) + ly * 8;
  const float* pJ = (wave ? sBJ_ : sAJ_) + lx * 8;

  for (int k0 = 0; k0 < DIM; k0 += BK) {
    __syncthreads();
    // stage 4 panels, [k][row] layout; each ds_write wave covers all 32 banks
    for (int h = 0; h < 4; ++h) {
      int cc = (h * 2 + wave) * 4;             // k-quad 0..7
      f32x4 va_i = *(const f32x4*)(fa + (size_t)(i0 + rr) * DIM + k0 + cc);
      f32x4 va_j = *(const f32x4*)(fa + (size_t)(j0 + rr) * DIM + k0 + cc);
      f32x4 vb_i = *(const f32x4*)(fb + (size_t)(i0 + rr) * DIM + k0 + cc);
      f32x4 vb_j = *(const f32x4*)(fb + (size_t)(j0 + rr) * DIM + k0 + cc);
#pragma unroll
      for (int u = 0; u < 4; ++u) {
        sAI_[(cc + u) * LDP + rr] = va_i[u];
        sAJ_[(cc + u) * LDP + rr] = va_j[u];
        sBI_[(cc + u) * LDP + rr] = vb_i[u];
        sBJ_[(cc + u) * LDP + rr] = vb_j[u];
      }
    }
    __syncthreads();

#pragma unroll 2
    for (int kk = 0; kk < BK; ++kk) {
      f32x4 vI0 = *(const f32x4*)(pI + kk * LDP);
      f32x4 vI1 = *(const f32x4*)(pI + kk * LDP + 4);
      f32x4 vJ0 = *(const f32x4*)(pJ + kk * LDP);
      f32x4 vJ1 = *(const f32x4*)(pJ + kk * LDP + 4);
      ROWS8(FMA_ROW)
    }
    // f64 flush per BK chunk (frozen cadence)
    ROWS8(FLUSH_ROW)
  }

  __syncthreads();   // staging LDS dead; safe to reuse as dbufB

  double accD[8][8];
  ROWS8(STORE_ROW)

  // ---- distances (fp16-quantized) + per-thread stats ----
  const double* sqx = ws + (wave ? WS_SQB : WS_SQA);
  double*       ux  = ws + (wave ? WS_U_B : WS_U_A);

  double si[8], sj[8];
#pragma unroll
  for (int m = 0; m < 8; ++m) si[m] = sqx[i0 + ly * 8 + m];
#pragma unroll
  for (int l = 0; l < 8; ++l) sj[l] = sqx[j0 + lx * 8 + l];

  double rs[8] = {0,0,0,0,0,0,0,0}, cs[8] = {0,0,0,0,0,0,0,0};
  double self = 0.0;
  u16x8 pk[8];
#pragma unroll
  for (int m = 0; m < 8; ++m) {
#pragma unroll
    for (int l = 0; l < 8; ++l) {
      double d2 = si[m] + sj[l] - 2.0 * accD[m][l];
      unsigned short bits = 0;
      double dq = 0.0;
      if (d2 > 0.0) {
        float df = (float)sqrt(d2);
        __half h = __float2half(df);          // RNE — frozen quantization
        bits = __half_as_ushort(h);
        dq = (double)__half2float(h);
      }
      if (diag && (ly * 8 + m == lx * 8 + l)) { bits = 0; dq = 0.0; }
      pk[m][l] = bits;
      rs[m] += dq;
      cs[l] += dq;
      self  += dq * dq;
    }
  }
  if (wave == 1) {
#pragma unroll
    for (int m = 0; m < 8; ++m)
      *(u16x8*)(dbufB + (size_t)(ly * 8 + m) * 72 + lx * 8) = pk[m];
  }

  // row sums -> u[i0+row] (reduce over lx: xor 1,2,4 — tree identical to prior rounds)
#pragma unroll
  for (int m = 0; m < 8; ++m) {
    double v = rs[m];
    v += __shfl_xor(v, 1); v += __shfl_xor(v, 2); v += __shfl_xor(v, 4);
    if (lx == 0) atomicAdd(&ux[i0 + ly * 8 + m], v);
  }
  if (!diag) {  // transposed entries: col sums -> u[j0+col] (reduce over ly)
#pragma unroll
    for (int l = 0; l < 8; ++l) {
      double v = cs[l];
      v += __shfl_xor(v, 8); v += __shfl_xor(v, 16); v += __shfl_xor(v, 32);
      if (ly == 0) atomicAdd(&ux[j0 + lx * 8 + l], v);
    }
  }

  __syncthreads();   // dbufB fully written

  double pab = 0.0;
  if (wave == 0) {
#pragma unroll
    for (int m = 0; m < 8; ++m) {
      u16x8 db = *(const u16x8*)(dbufB + (size_t)(ly * 8 + m) * 72 + lx * 8);
#pragma unroll
      for (int l = 0; l < 8; ++l)
        pab += (double)__half2float(__ushort_as_half(pk[m][l]))
             * (double)__half2float(__ushort_as_half(db[l]));
    }
  }

  for (int off = 32; off; off >>= 1) {
    pab  += __shfl_down(pab, off);
    self += __shfl_down(self, off);
  }
  if (lane == 0) {
    wred[wave][0] = (wave == 0) ? pab  : self;   // wave0: pab, wave1: pbb
    wred[wave][1] = (wave == 0) ? self : 0.0;    // wave0: paa
  }
  __syncthreads();
  if (t == 0) {
    double w = diag ? 1.0 : 2.0;
    ws[WS_PAB + blockIdx.x] = w * wred[0][0];
    ws[WS_PAA + blockIdx.x] = w * wred[0][1];
    ws[WS_PBB + blockIdx.x] = w * wred[1][0];
  }
}

// ---------------- final: reduce stats, closed-form U-centered dots --------------------
__global__ __launch_bounds__(256) void final_kernel(const double* __restrict__ ws,
                                                    float* __restrict__ out)
{
  const int t = threadIdx.x;
  double sa = 0, sb = 0, uab = 0, uaa = 0, ubb = 0, ab = 0, aa = 0, bb = 0;
  for (int i = t; i < NPTS; i += 256) {
    double a = ws[WS_U_A + i], b = ws[WS_U_B + i];
    sa += a; sb += b; uab += a * b; uaa += a * a; ubb += b * b;
  }
  for (int i = t; i < NTILES; i += 256) {
    ab += ws[WS_PAB + i]; aa += ws[WS_PAA + i]; bb += ws[WS_PBB + i];
  }
  for (int off = 32; off; off >>= 1) {
    sa  += __shfl_down(sa, off);  sb  += __shfl_down(sb, off);
    uab += __shfl_down(uab, off); uaa += __shfl_down(uaa, off); ubb += __shfl_down(ubb, off);
    ab  += __shfl_down(ab, off);  aa  += __shfl_down(aa, off);  bb  += __shfl_down(bb, off);
  }
  __shared__ double red[4][8];
  int wave = t >> 6, lane = t & 63;
  if (lane == 0) {
    red[wave][0] = sa;  red[wave][1] = sb;  red[wave][2] = uab; red[wave][3] = uaa;
    red[wave][4] = ubb; red[wave][5] = ab;  red[wave][6] = aa;  red[wave][7] = bb;
  }
  __syncthreads();
  if (t == 0) {
    double v[8] = {0,0,0,0,0,0,0,0};
    for (int q = 0; q < 4; ++q) for (int z = 0; z < 8; ++z) v[z] += red[q][z];
    const double SA = v[0], SB = v[1], UAB = v[2], UAA = v[3], UBB = v[4];
    const double PAB = v[5], PAA = v[6], PBB = v[7];
    const double n = (double)NPTS, nm2 = n - 2.0;
    auto dotv = [&](double P, double U, double sx, double sy) {
      double tX = sx / ((n - 1.0) * nm2), tY = sy / ((n - 1.0) * nm2);
      double RX = sx / nm2, RY = sy / nm2;
      double su  = U / nm2;
      double srr = U / (nm2 * nm2);
      double full = P - 4.0 * su + tY * sx + tX * sy + 2.0 * n * srr + 2.0 * RX * RY
                  - 2.0 * n * tY * RX - 2.0 * n * tX * RY + n * n * tX * tY;
      double dg = n * tX * tY - 2.0 * tX * RY - 2.0 * tY * RX + 4.0 * srr;
      return full - dg;
    };
    const double denomc = n * (n - 3.0);
    double dab = dotv(PAB, UAB, SA, SB) / denomc;
    double daa = dotv(PAA, UAA, SA, SA) / denomc;
    double dbb = dotv(PBB, UBB, SB, SB) / denomc;
    double dn = sqrt(daa * dbb);
    if (dn < 1e-9) dn = 1e-9;
    out[0] = (float)(dab / dn);
  }
}

extern "C" void kernel_launch(void* const* d_in, const int* in_sizes, int n_in,
                              void* d_out, int out_size, void* d_ws, size_t ws_size,
                              hipStream_t stream) {
  const float* fa = (const float*)d_in[0];
  const float* fb = (const float*)d_in[1];
  double* ws = (double*)d_ws;

  hipMemsetAsync(d_ws, 0, WS_ZERO_DOUBLES * sizeof(double), stream);
  sq_kernel<<<dim3(NPTS / 4, 2), 256, 0, stream>>>(fa, fb, ws);
  gram_kernel<<<NTILES, 128, 0, stream>>>(fa, fb, ws);
  final_kernel<<<1, 256, 0, stream>>>(ws, (float*)d_out);
}